// Round 5
// baseline (263.838 us; speedup 1.0000x reference)
//
#include <hip/hip_runtime.h>
#include <math.h>

// SoftMSM loss on MI355X — round 4.
// E-space linear DP (exact exp-space softmin3) + hard gate + skewed wave
// pipeline, now FOUR rows per super-step:
//   - steps 575 -> 191: shuffle/rebase/normalize paid once per 4 rows
//   - row q+1's weight phase (8 independent exps) overlaps row q's serial
//     FMA chain -> in-wave ILP at 1 wave/SIMD
//   - row data (xc, dx, ex2) as float4 quads in LDS, padded idx p+(p>>3)
//     (kills the 16B-stride 8-way bank conflict), prefetched 1 step ahead
//   - normalize max includes ALL carried boundary values (multi-row carries
//     can span huge ratios; keeping them in the max bounds everything <= 1)
//   - partials to d_ws + tiny reduce kernel (no atomics, no zero-init dep)
//
// Recursion (c=1, gamma=1), F = e^{i+j} * exp(-cost):
//   F[i,j] = F[i-1,j-1]*A + F[i-1,j]*B + F[i,j-1]*C
//   A = e^{2-m2}; B = (dx*(x-y)>0 ? ex2+Em : 1); C = (dy*(x-y)<0 ? edy2+Em : 1)
//   cost = 1022 - log(F[511,511])

#define TT 512
#define BATCH 64
#define G 8
#define R 4
#define NP (TT / R)              // 128 row-quads
#define STEPS (NP + 63)          // 191

#define C1F 1.2011224087864498f  // sqrt(log2 e)
#define C2F 2.8853900817779268f  // 2*log2 e
#define K2F 0.13533528323661270f // e^-2
#define LN2F 0.69314718055994531f

#if __has_builtin(__builtin_amdgcn_exp2f)
#define EXP2F(x) __builtin_amdgcn_exp2f(x)
#else
#define EXP2F(x) __expf((x) * LN2F)
#endif

#define QIDX(p) ((p) + ((p) >> 3))   // pad: breaks p <-> p+8 bank aliasing

__global__ __launch_bounds__(64) void msm_kernel(const float* __restrict__ x,
                                                 const float* __restrict__ y,
                                                 float* __restrict__ ws) {
  const int b = blockIdx.x;
  const int j = threadIdx.x;           // 0..63
  const int base = j * G;

  __shared__ float4 XC4[NP + (NP >> 3)];   // xc = x * C1, rows 4p..4p+3
  __shared__ float4 DX4[NP + (NP >> 3)];   // dx
  __shared__ float4 EX4[NP + (NP >> 3)];   // exp(-dx^2)

  // ---- setup: x-derived row data ----
  {
    const float4* xv = (const float4*)(x + b * TT);
    float4 a0 = xv[j * 2], a1 = xv[j * 2 + 1];
    float rx[G] = {a0.x, a0.y, a0.z, a0.w, a1.x, a1.y, a1.z, a1.w};
    float prev = (base > 0) ? x[b * TT + base - 1] : 0.0f;
    float cc[G], dd[G], ee[G];
#pragma unroll
    for (int k = 0; k < G; ++k) {
      float dx = rx[k] - prev;         // row 0's dx unused (up input is 0)
      prev = rx[k];
      cc[k] = rx[k] * C1F;
      dd[k] = dx;
      ee[k] = __expf(-dx * dx);
    }
    XC4[QIDX(j * 2)]     = make_float4(cc[0], cc[1], cc[2], cc[3]);
    XC4[QIDX(j * 2 + 1)] = make_float4(cc[4], cc[5], cc[6], cc[7]);
    DX4[QIDX(j * 2)]     = make_float4(dd[0], dd[1], dd[2], dd[3]);
    DX4[QIDX(j * 2 + 1)] = make_float4(dd[4], dd[5], dd[6], dd[7]);
    EX4[QIDX(j * 2)]     = make_float4(ee[0], ee[1], ee[2], ee[3]);
    EX4[QIDX(j * 2 + 1)] = make_float4(ee[4], ee[5], ee[6], ee[7]);
  }
  // ---- setup: y-derived column registers ----
  float yc[G], dyS[G], edy2[G];
  {
    const float4* yv = (const float4*)(y + b * TT);
    float4 a0 = yv[j * 2], a1 = yv[j * 2 + 1];
    float ry[G] = {a0.x, a0.y, a0.z, a0.w, a1.x, a1.y, a1.z, a1.w};
    float ym1 = (base > 0) ? y[b * TT + base - 1] : 0.0f;
#pragma unroll
    for (int k = 0; k < G; ++k) {
      yc[k] = ry[k] * C1F;
      float dy = ry[k] - ym1;          // col 0's dy unused (left input is 0)
      dyS[k] = dy;
      edy2[k] = __expf(-dy * dy);
      ym1 = ry[k];
    }
  }
  __syncthreads();

  float Ep[G];                         // F[a-1, base..base+7] (last done row)
#pragma unroll
  for (int k = 0; k < G; ++k) Ep[k] = 0.0f;
  // carried last-col values: dc0=lastcol(a-1), dc1..dc4=lastcol(a..a+3)
  float dc0 = 0.0f, dc1 = 0.0f, dc2 = 0.0f, dc3 = 0.0f, dc4 = 0.0f;
  int kacc = 0;                        // F_true = stored * 2^kacc

  // prefetch quad 0
  float4 nxc = XC4[QIDX(0)], ndx = DX4[QIDX(0)], nex = EX4[QIDX(0)];

  for (int t = 0; t < STEPS; ++t) {
    // boundary exchange (wave-lockstep, unconditional)
    float r0 = __shfl_up(dc0, 1);
    float r1 = __shfl_up(dc1, 1);
    float r2 = __shfl_up(dc2, 1);
    float r3 = __shfl_up(dc3, 1);
    float r4 = __shfl_up(dc4, 1);
    int k_in = __shfl_up(kacc, 1);
    const int p = t - j;               // my row-quad index
    if (j == 0) {
      r0 = (p == 0) ? K2F : 0.0f;      // virtual seed F[-1,-1]=e^{-2}
      r1 = r2 = r3 = r4 = 0.0f;
      k_in = kacc;
    }
    // rotate prefetched row data; prefetch next quad
    float4 cxc = nxc, cdx = ndx, cex = nex;
    {
      int pn = t + 1 - j;
      pn = (pn < 0) ? 0 : ((pn > NP - 1) ? NP - 1 : pn);
      int qi = QIDX(pn);
      nxc = XC4[qi]; ndx = DX4[qi]; nex = EX4[qi];
    }

    if (p >= 0 && p < NP) {
      if (p == 0) kacc = k_in;         // pipeline entry: adopt neighbor scale
      const int knew = (k_in > kacc) ? k_in : kacc;
      const float mMe = ldexpf(1.0f, kacc - knew);  // <= 1: no overflow
      const float mIn = ldexpf(1.0f, k_in - knew);  // <= 1
      kacc = knew;
      float dv0 = r0 * mIn, dv1 = r1 * mIn, dv2 = r2 * mIn,
            dv3 = r3 * mIn, dv4 = r4 * mIn;
      const float d0c = dc4 * mMe;     // lastcol(a-1) for next step's send
#pragma unroll
      for (int k = 0; k < G; ++k) Ep[k] *= mMe;

      float EnA[G], EnB[G];
      float lc0, lc1, lc2, lc3;

      // one DP row: weights phase (8 indep exps) then serial chain
      auto do_row = [&](float xc, float dxr, float ex2, float diag, float left,
                        const float* up, float* en) {
        float Av[G], Bv[G], Cv[G];
#pragma unroll
        for (int k = 0; k < G; ++k) {
          float s1 = xc - yc[k];                       // (x-y)*sqrt(log2e)
          float A = EXP2F(__fmaf_rn(s1, -s1, C2F));    // e^{2-m2}
          float Em = A * K2F;                          // e^{-m2}
          Av[k] = A;
          Bv[k] = (dxr * s1 > 0.0f) ? (ex2 + Em) : 1.0f;
          Cv[k] = (dyS[k] * s1 < 0.0f) ? (edy2[k] + Em) : 1.0f;
        }
#pragma unroll
        for (int k = 0; k < G; ++k) {
          float e = __fmaf_rn(left, Cv[k], __fmaf_rn(diag, Av[k], up[k] * Bv[k]));
          diag = up[k];
          left = e;
          en[k] = e;
        }
      };

      do_row(cxc.x, cdx.x, cex.x, dv0, dv1, Ep,  EnA); lc0 = EnA[G - 1];
      do_row(cxc.y, cdx.y, cex.y, dv1, dv2, EnA, EnB); lc1 = EnB[G - 1];
      do_row(cxc.z, cdx.z, cex.z, dv2, dv3, EnB, EnA); lc2 = EnA[G - 1];
      do_row(cxc.w, cdx.w, cex.w, dv3, dv4, EnA, EnB); lc3 = EnB[G - 1];

#pragma unroll
      for (int k = 0; k < G; ++k) Ep[k] = EnB[k];
      dc0 = d0c; dc1 = lc0; dc2 = lc1; dc3 = lc2; dc4 = lc3;

      // normalize: max over ALL carried state -> everything <= 1 afterwards
      float vmax = fmaxf(fmaxf(fmaxf(Ep[0], Ep[1]), fmaxf(Ep[2], Ep[3])),
                         fmaxf(fmaxf(Ep[4], Ep[5]), fmaxf(Ep[6], Ep[7])));
      vmax = fmaxf(vmax, fmaxf(fmaxf(dc0, dc1), fmaxf(dc2, dc3)));
      unsigned ue = (__float_as_uint(vmax) >> 23) & 0xFFu;
      int e = (int)ue - 126;                  // vmax>0 always in active lanes
      float sc = ldexpf(1.0f, -e);
#pragma unroll
      for (int k = 0; k < G; ++k) Ep[k] *= sc;
      dc0 *= sc; dc1 *= sc; dc2 *= sc; dc3 *= sc;
      dc4 = Ep[G - 1];
      kacc += e;
    }
  }

  if (j == 63) {
    // cost = 1022 - log(F_true)
    ws[b] = 1022.0f - (__logf(Ep[G - 1]) + (float)kacc * LN2F);
  }
}

__global__ __launch_bounds__(64) void reduce_kernel(const float* __restrict__ ws,
                                                    float* __restrict__ out) {
  float v = ws[threadIdx.x];
#pragma unroll
  for (int off = 32; off > 0; off >>= 1) v += __shfl_down(v, off);
  if (threadIdx.x == 0) out[0] = v * (1.0f / BATCH);
}

extern "C" void kernel_launch(void* const* d_in, const int* in_sizes, int n_in,
                              void* d_out, int out_size, void* d_ws, size_t ws_size,
                              hipStream_t stream) {
  const float* x = (const float*)d_in[0];
  const float* y = (const float*)d_in[1];
  float* ws = (float*)d_ws;
  float* out = (float*)d_out;
  msm_kernel<<<BATCH, 64, 0, stream>>>(x, y, ws);
  reduce_kernel<<<1, 64, 0, stream>>>(ws, out);
}